// Round 7
// baseline (163.555 us; speedup 1.0000x reference)
//
#include <hip/hip_runtime.h>

#define LOG2E 1.4426950408889634f

typedef __bf16 bf16x8 __attribute__((ext_vector_type(8)));
typedef float f32x4 __attribute__((ext_vector_type(4)));
typedef float f32x2 __attribute__((ext_vector_type(2)));
typedef unsigned short u16x8 __attribute__((ext_vector_type(8)));

__device__ __forceinline__ unsigned short bfb(__bf16 b){
  union { __bf16 b; unsigned short u; } z; z.b = b; return z.u;
}

// Packed-B layout: element (n,k) hi/lo -> ((nt*16+ks)*2+hl)*512 + lane*8 + j
//   nt=n>>4, ln=n&15, ks=k>>5, q=(k&31)>>3, j=k&7, lane=q*16+ln

// ---------------- prep: W2 fold, Wv/Wo split, biases, A-planes, O/den zero ----------
__global__ __launch_bounds__(256) void prep_all(
    const float* __restrict__ Wq, const float* __restrict__ Aq,
    const float* __restrict__ Wk, const float* __restrict__ Ak,
    const float* __restrict__ bq, const float* __restrict__ bk,
    const float* __restrict__ av,
    const float* __restrict__ Wv, const float* __restrict__ Wo,
    const float* __restrict__ Qin, const float* __restrict__ Kin,
    const float* __restrict__ Vin,
    unsigned short* __restrict__ W2qp, unsigned short* __restrict__ W2kp,
    unsigned short* __restrict__ Wvp,  unsigned short* __restrict__ Wop,
    unsigned short* __restrict__ qhi, unsigned short* __restrict__ qlo,
    unsigned short* __restrict__ khi, unsigned short* __restrict__ klo,
    unsigned short* __restrict__ vhi, unsigned short* __restrict__ vlo,
    float* __restrict__ b2q, float* __restrict__ b2k, float* __restrict__ av2g,
    float* __restrict__ zbase){
  if (blockIdx.x >= 513){
    if (blockIdx.y){
      // ---- zero den (8192 f32) + O (524288 f32), contiguous at zbase ----
      int x = blockIdx.x - 513;
      if (x < 260){
        float* z = zbase + (size_t)(x * 256 + threadIdx.x) * 8;
        f32x4 zz = {0.f, 0.f, 0.f, 0.f};
        *(f32x4*)z = zz;
        *(f32x4*)(z + 4) = zz;
      }
      return;
    }
    // ---- A-plane conversion: f32 -> bf16 hi/lo, 8 elems/thread ----
    int j = blockIdx.x - 513;                 // 0..767
    const float* src; unsigned short *dh, *dl;
    if (j < 256){ src = Qin; dh = qhi; dl = qlo; }
    else if (j < 512){ src = Kin; dh = khi; dl = klo; j -= 256; }
    else { src = Vin; dh = vhi; dl = vlo; j -= 512; }
    int base = (j * 256 + threadIdx.x) * 8;
    f32x4 v0 = *(const f32x4*)(src + base);
    f32x4 v1 = *(const f32x4*)(src + base + 4);
    u16x8 hh, ll;
    #pragma unroll
    for (int t = 0; t < 8; t++){
      float f = (t < 4) ? v0[t] : v1[t - 4];
      __bf16 hb = (__bf16)f;
      hh[t] = bfb(hb);
      ll[t] = bfb((__bf16)(f - (float)hb));
    }
    *(u16x8*)(dh + base) = hh;
    *(u16x8*)(dl + base) = ll;
    return;
  }
  if (blockIdx.x >= 256){
    if (blockIdx.x == 512){
      if (blockIdx.y == 0){
        #pragma unroll
        for (int rep = 0; rep < 2; rep++){
          int n = rep * 256 + threadIdx.x;
          int h = n >> 6, e = n & 63;
          float aq = 0.f, ak = 0.f;
          for (int c = 0; c < 64; c++){
            aq += Aq[e*64 + c] * bq[h*64 + c];
            ak += Ak[e*64 + c] * bk[h*64 + c];
          }
          b2q[n] = aq * (2.f * LOG2E);
          b2k[n] = ak * (2.f * LOG2E);
        }
      } else {
        if (threadIdx.x < 64) av2g[threadIdx.x] = -2.f * LOG2E * av[threadIdx.x];
      }
      return;
    }
    const float* src = blockIdx.y ? Wo : Wv;
    unsigned short* dst = blockIdx.y ? Wop : Wvp;
    int base = ((blockIdx.x - 256) * 256 + threadIdx.x) * 4;
    int n = base >> 9, k0 = base & 511;
    float4 v = *(const float4*)(src + base);
    ushort4 h, l;
    float f; __bf16 hb;
    f = v.x; hb = (__bf16)f; h.x = bfb(hb); l.x = bfb((__bf16)(f - (float)hb));
    f = v.y; hb = (__bf16)f; h.y = bfb(hb); l.y = bfb((__bf16)(f - (float)hb));
    f = v.z; hb = (__bf16)f; h.z = bfb(hb); l.z = bfb((__bf16)(f - (float)hb));
    f = v.w; hb = (__bf16)f; h.w = bfb(hb); l.w = bfb((__bf16)(f - (float)hb));
    int nt = n >> 4, ln = n & 15;
    int ks = k0 >> 5, q = (k0 & 31) >> 3, j0 = k0 & 7;
    size_t off = (size_t)((nt*16 + ks) * 2) * 512 + (q*16 + ln) * 8 + j0;
    *(ushort4*)(dst + off)       = h;
    *(ushort4*)(dst + off + 512) = l;
    return;
  }
  // W2 fold: idx -> (n, 4 consecutive k)
  const float* W  = blockIdx.y ? Wk : Wq;
  const float* Am = blockIdx.y ? Ak : Aq;
  unsigned short* dst = blockIdx.y ? W2kp : W2qp;
  int idx = blockIdx.x * 256 + threadIdx.x;   // 0..65535
  int n = idx >> 7;                            // 0..511 (wave-uniform)
  int k0 = (idx & 127) * 4;                    // 0..508 step 4
  int h = n >> 6, e = n & 63;
  float4 acc = {0.f, 0.f, 0.f, 0.f};
  #pragma unroll 8
  for (int c = 0; c < 64; c++){
    float am = Am[e*64 + c];
    float4 wv = *(const float4*)(W + (size_t)(h*64 + c)*512 + k0);
    acc.x += am * wv.x;
    acc.y += am * wv.y;
    acc.z += am * wv.z;
    acc.w += am * wv.w;
  }
  int nt = n >> 4, ln = n & 15;
  int ks = k0 >> 5, q = (k0 & 31) >> 3, j0 = k0 & 7;
  size_t off = (size_t)((nt*16 + ks) * 2) * 512 + (q*16 + ln) * 8 + j0;
  ushort4 hh, ll;
  float f; __bf16 hb;
  f = acc.x * (2.f * LOG2E); hb = (__bf16)f; hh.x = bfb(hb); ll.x = bfb((__bf16)(f - (float)hb));
  f = acc.y * (2.f * LOG2E); hb = (__bf16)f; hh.y = bfb(hb); ll.y = bfb((__bf16)(f - (float)hb));
  f = acc.z * (2.f * LOG2E); hb = (__bf16)f; hh.z = bfb(hb); ll.z = bfb((__bf16)(f - (float)hb));
  f = acc.w * (2.f * LOG2E); hb = (__bf16)f; hh.w = bfb(hb); ll.w = bfb((__bf16)(f - (float)hb));
  *(ushort4*)(dst + off)       = hh;
  *(ushort4*)(dst + off + 512) = ll;
}

// ---------------- MFMA GEMM: reg-double-buffered A (pre-split bf16 planes), packed B ----
struct GemmBatch {
  const unsigned short* Ahi;
  const unsigned short* Alo;
  const unsigned short* Bp;
  const float* bias;
  float* Cf;
  unsigned short* Chi;           // dual-plane transposed output (V)
  unsigned short* Clo;
  int transposed;                // 1: eqQ layout [bh][q][d] contiguous f32
  int expout;                    // 1: store exp2(val)
  int dual;                      // 1: transposed dual-plane bf16 [bh][d][j]
};
struct GemmArgs { GemmBatch g[3]; };

__global__ __launch_bounds__(256) void gemm_nk(GemmArgs ga){
  GemmBatch gb = ga.g[blockIdx.z];
  __shared__ unsigned short AhiS[32 * 72];
  __shared__ unsigned short AloS[32 * 72];
  const int tid = threadIdx.x, lane = tid & 63, w = tid >> 6;
  const int l15 = lane & 15, quad = lane >> 4;
  const int m0  = blockIdx.x * 32;
  const int nt0 = blockIdx.y * 4;
  const int wr = w >> 1, wc = w & 1;
  f32x4 ac0 = {0.f,0.f,0.f,0.f}, ac1 = ac0;

  const int srow = tid >> 3;            // 0..31
  const int scol = (tid & 7) * 8;       // 0..56
  const unsigned short* srcH = gb.Ahi + (size_t)(m0 + srow) * 512 + scol;
  const unsigned short* srcL = gb.Alo + (size_t)(m0 + srow) * 512 + scol;
  unsigned short* dstH = &AhiS[srow * 72 + scol];
  unsigned short* dstL = &AloS[srow * 72 + scol];
  u16x8 ph = *(const u16x8*)srcH;       // kc=0 prefetch
  u16x8 pl = *(const u16x8*)srcL;

  const int arow = (wr * 16 + l15) * 72;

  for (int kc = 0; kc < 8; kc++){
    __syncthreads();
    *(u16x8*)dstH = ph;
    *(u16x8*)dstL = pl;
    if (kc < 7){
      ph = *(const u16x8*)(srcH + (kc + 1) * 64);   // latency spans compute phase
      pl = *(const u16x8*)(srcL + (kc + 1) * 64);
    }
    __syncthreads();
    #pragma unroll
    for (int s = 0; s < 2; s++){
      int ks = kc * 2 + s;
      bf16x8 ah = *(const bf16x8*)&AhiS[arow + s*32 + quad*8];
      bf16x8 al = *(const bf16x8*)&AloS[arow + s*32 + quad*8];
      #pragma unroll
      for (int t = 0; t < 2; t++){
        int nt = nt0 + wc*2 + t;
        const unsigned short* bp = gb.Bp + (size_t)((nt*16 + ks) * 2) * 512 + lane*8;
        bf16x8 bh = *(const bf16x8*)bp;
        bf16x8 bl = *(const bf16x8*)(bp + 512);
        f32x4& ac = t ? ac1 : ac0;
        ac = __builtin_amdgcn_mfma_f32_16x16x32_bf16(ah, bh, ac, 0, 0, 0);
        ac = __builtin_amdgcn_mfma_f32_16x16x32_bf16(al, bh, ac, 0, 0, 0);
        ac = __builtin_amdgcn_mfma_f32_16x16x32_bf16(ah, bl, ac, 0, 0, 0);
      }
    }
  }

  const int mrow = m0 + wr * 16 + quad * 4;
  #pragma unroll
  for (int t = 0; t < 2; t++){
    f32x4 v = t ? ac1 : ac0;
    int n = nt0*16 + wc*32 + t*16 + l15;
    float bs = gb.bias[n];
    #pragma unroll
    for (int r = 0; r < 4; r++){
      float val = v[r] + bs;
      if (gb.expout) val = __builtin_amdgcn_exp2f(val);
      int m2 = mrow + r;
      if (gb.dual){
        // V transposed dual-plane: [bh][d][j], bh=(m2>>9)*8+(n>>6), d=n&63, j=m2&511
        size_t o = (size_t)(((m2 >> 9) * 8 + (n >> 6)) * 64 + (n & 63)) * 512 + (m2 & 511);
        __bf16 hb = (__bf16)val;
        gb.Chi[o] = bfb(hb);
        gb.Clo[o] = bfb((__bf16)(val - (float)hb));
      } else if (gb.transposed){
        // eqQ layout: [bh][q][d]
        gb.Cf[(size_t)(((m2 >> 9) * 8 + (n >> 6)) * 512 + (m2 & 511)) * 64 + (n & 63)] = val;
      } else {
        gb.Cf[(size_t)m2 * 512 + n] = val;
      }
    }
  }
}

// ---------------- score + PV: tiled streaming scores, in-LDS P, MFMA PV, atomic O ----
// grid (4 j-tiles, 8 i-tiles, 16 bh), 256 thr. LDS ~49.9KB -> 3 blocks/CU.
__global__ __launch_bounds__(256, 3) void score_pv(
    const float* __restrict__ eqQ, const float* __restrict__ ekp,
    const float* __restrict__ av2g,
    const unsigned short* __restrict__ vthi, const unsigned short* __restrict__ vtlo,
    float* __restrict__ Og, float* __restrict__ deng){
  __shared__ float SHf[12480];                       // 49920 B
  float* EKt = SHf;                                  // [64][130] f32 (33280 B)
  float* EQs = SHf + 8320;                           // [64][64]  f32 (16384 B)
  float* avS = SHf + 12416;                          // [64]
  unsigned short* Ph = (unsigned short*)SHf;         // [64][136] bf16 (17408 B) — aliases EKt
  unsigned short* Pl = (unsigned short*)SHf + 8704;  // second plane (17408 B)

  const int tid = threadIdx.x, lane = tid & 63, w = tid >> 6;
  const int l15 = lane & 15, quad = lane >> 4;
  const int bh = blockIdx.z, b = bh >> 3, h = bh & 7;
  const int i0 = blockIdx.y * 64;
  const int j0 = blockIdx.x * 128;

  { // stage EQ [i][d]
    int r = tid >> 2, c = (tid & 3) * 16;
    const float* s = eqQ + ((size_t)bh * 512 + i0 + r) * 64 + c;
    #pragma unroll
    for (int u = 0; u < 4; u++)
      *(f32x4*)&EQs[r * 64 + c + u * 4] = *(const f32x4*)(s + u * 4);
  }
  if (tid < 64) avS[tid] = av2g[tid];
  { // stage EK transposed [d][j]
    int j = tid >> 1, c0 = (tid & 1) * 32;
    const float* s = ekp + ((size_t)(b * 512) + j0 + j) * 512 + h * 64 + c0;
    #pragma unroll
    for (int u = 0; u < 8; u++){
      f32x4 v = *(const f32x4*)(s + u * 4);
      #pragma unroll
      for (int q = 0; q < 4; q++) EKt[(c0 + u * 4 + q) * 130 + j] = v[q];
    }
  }
  __syncthreads();

  // score: wave w -> 16 i rows; lane -> 2 consecutive j
  f32x2 acc[16];
  #pragma unroll
  for (int ii = 0; ii < 16; ii++) acc[ii] = (f32x2){0.f, 0.f};
  for (int d = 0; d < 64; d += 4){
    f32x2 ek0 = *(const f32x2*)&EKt[(d    ) * 130 + 2 * lane];
    f32x2 ek1 = *(const f32x2*)&EKt[(d + 1) * 130 + 2 * lane];
    f32x2 ek2 = *(const f32x2*)&EKt[(d + 2) * 130 + 2 * lane];
    f32x2 ek3 = *(const f32x2*)&EKt[(d + 3) * 130 + 2 * lane];
    f32x4 a4 = *(const f32x4*)&avS[d];
    #pragma unroll
    for (int ii = 0; ii < 16; ii++){
      f32x4 eq4 = *(const f32x4*)&EQs[(w * 16 + ii) * 64 + d];
      f32x2 A = __builtin_elementwise_fma((f32x2){eq4[0], eq4[0]}, ek0, (f32x2){1.f, 1.f});
      f32x2 B = __builtin_elementwise_fma((f32x2){eq4[1], eq4[1]}, ek1, (f32x2){1.f, 1.f});
      f32x2 t = __builtin_elementwise_fma((f32x2){a4[1], a4[1]}, A, (f32x2){a4[0], a4[0]} * B);
      f32x2 dpr = A * B;
      f32x2 r;
      r.x = __builtin_amdgcn_rcpf(dpr.x);
      r.y = __builtin_amdgcn_rcpf(dpr.y);
      acc[ii] = __builtin_elementwise_fma(t, r, acc[ii]);
      f32x2 C = __builtin_elementwise_fma((f32x2){eq4[2], eq4[2]}, ek2, (f32x2){1.f, 1.f});
      f32x2 D = __builtin_elementwise_fma((f32x2){eq4[3], eq4[3]}, ek3, (f32x2){1.f, 1.f});
      f32x2 t2 = __builtin_elementwise_fma((f32x2){a4[3], a4[3]}, C, (f32x2){a4[2], a4[2]} * D);
      f32x2 dpr2 = C * D;
      f32x2 r2;
      r2.x = __builtin_amdgcn_rcpf(dpr2.x);
      r2.y = __builtin_amdgcn_rcpf(dpr2.y);
      acc[ii] = __builtin_elementwise_fma(t2, r2, acc[ii]);
    }
  }
  // exponentials (in regs), then barrier before overwriting EKt/EQs with P
  #pragma unroll
  for (int ii = 0; ii < 16; ii++){
    acc[ii].x = __builtin_amdgcn_exp2f(acc[ii].x);
    acc[ii].y = __builtin_amdgcn_exp2f(acc[ii].y);
  }
  __syncthreads();
  #pragma unroll
  for (int ii = 0; ii < 16; ii++){
    float s2 = acc[ii].x + acc[ii].y;
    #pragma unroll
    for (int off = 1; off < 64; off <<= 1) s2 += __shfl_xor(s2, off, 64);
    if (lane == 0) atomicAdd(&deng[bh * 512 + i0 + w * 16 + ii], s2);
    __bf16 h0 = (__bf16)acc[ii].x, h1 = (__bf16)acc[ii].y;
    ushort2 hi = { bfb(h0), bfb(h1) };
    ushort2 lo = { bfb((__bf16)(acc[ii].x - (float)h0)), bfb((__bf16)(acc[ii].y - (float)h1)) };
    *(ushort2*)&Ph[(w * 16 + ii) * 136 + 2 * lane] = hi;
    *(ushort2*)&Pl[(w * 16 + ii) * 136 + 2 * lane] = lo;
  }
  __syncthreads();

  // PV: per wave, i-strip 16 x all 64 d, K = 128 (this block's j tile)
  f32x4 o0 = {0.f,0.f,0.f,0.f}, o1 = o0, o2 = o0, o3 = o0;
  const size_t vbase = ((size_t)bh * 64) * 512 + j0;
  #pragma unroll
  for (int ks = 0; ks < 4; ks++){
    bf16x8 pa = *(const bf16x8*)&Ph[(w * 16 + l15) * 136 + ks * 32 + quad * 8];
    bf16x8 pb = *(const bf16x8*)&Pl[(w * 16 + l15) * 136 + ks * 32 + quad * 8];
    #pragma unroll
    for (int nt = 0; nt < 4; nt++){
      size_t vo = vbase + (size_t)(nt * 16 + l15) * 512 + ks * 32 + quad * 8;
      bf16x8 vh = *(const bf16x8*)(vthi + vo);
      bf16x8 vl = *(const bf16x8*)(vtlo + vo);
      f32x4& o = nt == 0 ? o0 : nt == 1 ? o1 : nt == 2 ? o2 : o3;
      o = __builtin_amdgcn_mfma_f32_16x16x32_bf16(pa, vh, o, 0, 0, 0);
      o = __builtin_amdgcn_mfma_f32_16x16x32_bf16(pb, vh, o, 0, 0, 0);
      o = __builtin_amdgcn_mfma_f32_16x16x32_bf16(pa, vl, o, 0, 0, 0);
    }
  }
  #pragma unroll
  for (int nt = 0; nt < 4; nt++){
    f32x4 o = nt == 0 ? o0 : nt == 1 ? o1 : nt == 2 ? o2 : o3;
    int d = nt * 16 + l15;
    #pragma unroll
    for (int r = 0; r < 4; r++){
      int i = i0 + w * 16 + quad * 4 + r;
      atomicAdd(&Og[((size_t)bh * 512 + i) * 64 + d], o[r]);
    }
  }
}

// ---------------- finish: O/den -> Oh bf16 hi/lo planes ----------------
__global__ __launch_bounds__(256) void finish_oh(
    const float* __restrict__ Og, const float* __restrict__ deng,
    unsigned short* __restrict__ Ohhi, unsigned short* __restrict__ Ohlo){
  int t = blockIdx.x * 256 + threadIdx.x;       // 0..65535
  int bh = t >> 12;
  int i  = (t >> 3) & 511;
  int d0 = (t & 7) * 8;
  float rv = 1.0f / deng[bh * 512 + i];
  const float* src = Og + ((size_t)bh * 512 + i) * 64 + d0;
  f32x4 v0 = *(const f32x4*)src;
  f32x4 v1 = *(const f32x4*)(src + 4);
  u16x8 hh, ll;
  #pragma unroll
  for (int u = 0; u < 8; u++){
    float f = ((u < 4) ? v0[u] : v1[u - 4]) * rv;
    __bf16 hb = (__bf16)f;
    hh[u] = bfb(hb);
    ll[u] = bfb((__bf16)(f - (float)hb));
  }
  size_t o = ((size_t)(bh >> 3) * 512 + i) * 512 + (bh & 7) * 64 + d0;
  *(u16x8*)(Ohhi + o) = hh;
  *(u16x8*)(Ohlo + o) = ll;
}

// ---------------- launch ----------------
extern "C" void kernel_launch(void* const* d_in, const int* in_sizes, int n_in,
                              void* d_out, int out_size, void* d_ws, size_t ws_size,
                              hipStream_t stream){
  const float* q_in = (const float*)d_in[0];
  const float* k_in = (const float*)d_in[1];
  const float* v_in = (const float*)d_in[2];
  const float* Wq_  = (const float*)d_in[3];
  const float* bq_  = (const float*)d_in[4];
  const float* Wk_  = (const float*)d_in[5];
  const float* bk_  = (const float*)d_in[6];
  const float* Wv_  = (const float*)d_in[7];
  const float* bv_  = (const float*)d_in[8];
  const float* Wo_  = (const float*)d_in[9];
  const float* bo_  = (const float*)d_in[10];
  const float* Aq_  = (const float*)d_in[11];
  const float* Ak_  = (const float*)d_in[12];
  const float* av_  = (const float*)d_in[13];

  char* ws = (char*)d_ws;
  unsigned short* W2qp = (unsigned short*)(ws + 0);
  unsigned short* W2kp = (unsigned short*)(ws + 1048576);
  unsigned short* Ohhi = (unsigned short*)(ws + 0);        // reuses W2 region after gemm1
  unsigned short* Ohlo = (unsigned short*)(ws + 1048576);
  unsigned short* Wvp  = (unsigned short*)(ws + 2097152);
  unsigned short* Wop  = (unsigned short*)(ws + 3145728);
  float* b2q  = (float*)(ws + 4194304);
  float* b2k  = (float*)(ws + 4196352);
  float* av2g = (float*)(ws + 4198400);
  float* eqQ  = (float*)(ws + 4198656);
  float* ekp  = (float*)(ws + 6295808);
  unsigned short* vthi = (unsigned short*)(ws + 8392960);
  unsigned short* vtlo = (unsigned short*)(ws + 9441536);
  unsigned short* qhi = (unsigned short*)(ws + 10490112);
  unsigned short* qlo = (unsigned short*)(ws + 11538688);
  unsigned short* khi = (unsigned short*)(ws + 12587264);
  unsigned short* klo = (unsigned short*)(ws + 13635840);
  unsigned short* vhi = (unsigned short*)(ws + 14684416);
  unsigned short* vlo = (unsigned short*)(ws + 15732992);
  float* deng = (float*)(ws + 16781568);     // 32KB
  float* Og   = (float*)(ws + 16814336);     // 2MB, contiguous after deng

  prep_all<<<dim3(1281, 2, 1), 256, 0, stream>>>(Wq_, Aq_, Wk_, Ak_, bq_, bk_, av_,
                                                 Wv_, Wo_, q_in, k_in, v_in,
                                                 W2qp, W2kp, Wvp, Wop,
                                                 qhi, qlo, khi, klo, vhi, vlo,
                                                 b2q, b2k, av2g, deng);

  GemmArgs ga;
  ga.g[0] = { qhi, qlo, W2qp, b2q, eqQ, 0, 0, 1, 1, 0 };
  ga.g[1] = { khi, klo, W2kp, b2k, ekp, 0, 0, 0, 1, 0 };
  ga.g[2] = { vhi, vlo, Wvp,  bv_, 0, vthi, vtlo, 0, 0, 1 };
  gemm_nk<<<dim3(32, 8, 3), 256, 0, stream>>>(ga);

  score_pv<<<dim3(4, 8, 16), 256, 0, stream>>>(eqQ, ekp, av2g, vthi, vtlo, Og, deng);

  finish_oh<<<dim3(256, 1, 1), 256, 0, stream>>>(Og, deng, Ohhi, Ohlo);

  GemmArgs go;
  go.g[0] = { Ohhi, Ohlo, Wop, bo_, (float*)d_out, 0, 0, 0, 0, 0 };
  go.g[1] = go.g[0];
  go.g[2] = go.g[0];
  gemm_nk<<<dim3(32, 8, 1), 256, 0, stream>>>(go);
}

// Round 8
// 157.420 us; speedup vs baseline: 1.0390x; 1.0390x over previous
//
#include <hip/hip_runtime.h>

#define LOG2E 1.4426950408889634f

typedef __bf16 bf16x8 __attribute__((ext_vector_type(8)));
typedef float f32x4 __attribute__((ext_vector_type(4)));
typedef float f32x2 __attribute__((ext_vector_type(2)));
typedef unsigned short u16x8 __attribute__((ext_vector_type(8)));

__device__ __forceinline__ unsigned short bfb(__bf16 b){
  union { __bf16 b; unsigned short u; } z; z.b = b; return z.u;
}

// Packed-B layout: element (n,k) hi/lo -> ((nt*16+ks)*2+hl)*512 + lane*8 + j
//   nt=n>>4, ln=n&15, ks=k>>5, q=(k&31)>>3, j=k&7, lane=q*16+ln

// ---------------- prep: W2 fold, Wv/Wo split, biases, A-planes, O/den zero ----------
__global__ __launch_bounds__(256) void prep_all(
    const float* __restrict__ Wq, const float* __restrict__ Aq,
    const float* __restrict__ Wk, const float* __restrict__ Ak,
    const float* __restrict__ bq, const float* __restrict__ bk,
    const float* __restrict__ av,
    const float* __restrict__ Wv, const float* __restrict__ Wo,
    const float* __restrict__ Qin, const float* __restrict__ Kin,
    const float* __restrict__ Vin,
    unsigned short* __restrict__ W2qp, unsigned short* __restrict__ W2kp,
    unsigned short* __restrict__ Wvp,  unsigned short* __restrict__ Wop,
    unsigned short* __restrict__ qhi, unsigned short* __restrict__ qlo,
    unsigned short* __restrict__ khi, unsigned short* __restrict__ klo,
    unsigned short* __restrict__ vhi, unsigned short* __restrict__ vlo,
    float* __restrict__ b2q, float* __restrict__ b2k, float* __restrict__ av2g,
    float* __restrict__ zbase){
  if (blockIdx.x >= 513){
    if (blockIdx.y){
      // ---- zero den (8192 f32) + O (524288 f32), contiguous at zbase ----
      int x = blockIdx.x - 513;
      if (x < 260){
        float* z = zbase + (size_t)(x * 256 + threadIdx.x) * 8;
        f32x4 zz = {0.f, 0.f, 0.f, 0.f};
        *(f32x4*)z = zz;
        *(f32x4*)(z + 4) = zz;
      }
      return;
    }
    // ---- A-plane conversion: f32 -> bf16 hi/lo, 8 elems/thread ----
    int j = blockIdx.x - 513;                 // 0..767
    const float* src; unsigned short *dh, *dl;
    if (j < 256){ src = Qin; dh = qhi; dl = qlo; }
    else if (j < 512){ src = Kin; dh = khi; dl = klo; j -= 256; }
    else { src = Vin; dh = vhi; dl = vlo; j -= 512; }
    int base = (j * 256 + threadIdx.x) * 8;
    f32x4 v0 = *(const f32x4*)(src + base);
    f32x4 v1 = *(const f32x4*)(src + base + 4);
    u16x8 hh, ll;
    #pragma unroll
    for (int t = 0; t < 8; t++){
      float f = (t < 4) ? v0[t] : v1[t - 4];
      __bf16 hb = (__bf16)f;
      hh[t] = bfb(hb);
      ll[t] = bfb((__bf16)(f - (float)hb));
    }
    *(u16x8*)(dh + base) = hh;
    *(u16x8*)(dl + base) = ll;
    return;
  }
  if (blockIdx.x >= 256){
    if (blockIdx.x == 512){
      if (blockIdx.y == 0){
        #pragma unroll
        for (int rep = 0; rep < 2; rep++){
          int n = rep * 256 + threadIdx.x;
          int h = n >> 6, e = n & 63;
          float aq = 0.f, ak = 0.f;
          for (int c = 0; c < 64; c++){
            aq += Aq[e*64 + c] * bq[h*64 + c];
            ak += Ak[e*64 + c] * bk[h*64 + c];
          }
          b2q[n] = aq * (2.f * LOG2E);
          b2k[n] = ak * (2.f * LOG2E);
        }
      } else {
        if (threadIdx.x < 64) av2g[threadIdx.x] = -2.f * LOG2E * av[threadIdx.x];
      }
      return;
    }
    const float* src = blockIdx.y ? Wo : Wv;
    unsigned short* dst = blockIdx.y ? Wop : Wvp;
    int base = ((blockIdx.x - 256) * 256 + threadIdx.x) * 4;
    int n = base >> 9, k0 = base & 511;
    float4 v = *(const float4*)(src + base);
    ushort4 h, l;
    float f; __bf16 hb;
    f = v.x; hb = (__bf16)f; h.x = bfb(hb); l.x = bfb((__bf16)(f - (float)hb));
    f = v.y; hb = (__bf16)f; h.y = bfb(hb); l.y = bfb((__bf16)(f - (float)hb));
    f = v.z; hb = (__bf16)f; h.z = bfb(hb); l.z = bfb((__bf16)(f - (float)hb));
    f = v.w; hb = (__bf16)f; h.w = bfb(hb); l.w = bfb((__bf16)(f - (float)hb));
    int nt = n >> 4, ln = n & 15;
    int ks = k0 >> 5, q = (k0 & 31) >> 3, j0 = k0 & 7;
    size_t off = (size_t)((nt*16 + ks) * 2) * 512 + (q*16 + ln) * 8 + j0;
    *(ushort4*)(dst + off)       = h;
    *(ushort4*)(dst + off + 512) = l;
    return;
  }
  // W2 fold: idx -> (n, 4 consecutive k)
  const float* W  = blockIdx.y ? Wk : Wq;
  const float* Am = blockIdx.y ? Ak : Aq;
  unsigned short* dst = blockIdx.y ? W2kp : W2qp;
  int idx = blockIdx.x * 256 + threadIdx.x;   // 0..65535
  int n = idx >> 7;                            // 0..511 (wave-uniform)
  int k0 = (idx & 127) * 4;                    // 0..508 step 4
  int h = n >> 6, e = n & 63;
  float4 acc = {0.f, 0.f, 0.f, 0.f};
  #pragma unroll 8
  for (int c = 0; c < 64; c++){
    float am = Am[e*64 + c];
    float4 wv = *(const float4*)(W + (size_t)(h*64 + c)*512 + k0);
    acc.x += am * wv.x;
    acc.y += am * wv.y;
    acc.z += am * wv.z;
    acc.w += am * wv.w;
  }
  int nt = n >> 4, ln = n & 15;
  int ks = k0 >> 5, q = (k0 & 31) >> 3, j0 = k0 & 7;
  size_t off = (size_t)((nt*16 + ks) * 2) * 512 + (q*16 + ln) * 8 + j0;
  ushort4 hh, ll;
  float f; __bf16 hb;
  f = acc.x * (2.f * LOG2E); hb = (__bf16)f; hh.x = bfb(hb); ll.x = bfb((__bf16)(f - (float)hb));
  f = acc.y * (2.f * LOG2E); hb = (__bf16)f; hh.y = bfb(hb); ll.y = bfb((__bf16)(f - (float)hb));
  f = acc.z * (2.f * LOG2E); hb = (__bf16)f; hh.z = bfb(hb); ll.z = bfb((__bf16)(f - (float)hb));
  f = acc.w * (2.f * LOG2E); hb = (__bf16)f; hh.w = bfb(hb); ll.w = bfb((__bf16)(f - (float)hb));
  *(ushort4*)(dst + off)       = hh;
  *(ushort4*)(dst + off + 512) = ll;
}

// ---------------- MFMA GEMM: reg-double-buffered A (pre-split bf16 planes), packed B ----
struct GemmBatch {
  const unsigned short* Ahi;
  const unsigned short* Alo;
  const unsigned short* Bp;
  const float* bias;
  float* Cf;
  unsigned short* Chi;           // dual-plane transposed output (V)
  unsigned short* Clo;
  int transposed;                // 1: eqQ layout [bh][q][d] contiguous f32
  int expout;                    // 1: store exp2(val)
  int dual;                      // 1: transposed dual-plane bf16 [bh][d][j]
};
struct GemmArgs { GemmBatch g[3]; };

__global__ __launch_bounds__(256) void gemm_nk(GemmArgs ga){
  GemmBatch gb = ga.g[blockIdx.z];
  __shared__ unsigned short AhiS[64 * 40];   // staging 32x72 fits; dual-epilogue needs 64x40
  __shared__ unsigned short AloS[64 * 40];
  const int tid = threadIdx.x, lane = tid & 63, w = tid >> 6;
  const int l15 = lane & 15, quad = lane >> 4;
  const int m0  = blockIdx.x * 32;
  const int nt0 = blockIdx.y * 4;
  const int wr = w >> 1, wc = w & 1;
  f32x4 ac0 = {0.f,0.f,0.f,0.f}, ac1 = ac0;

  const int srow = tid >> 3;            // 0..31
  const int scol = (tid & 7) * 8;       // 0..56
  const unsigned short* srcH = gb.Ahi + (size_t)(m0 + srow) * 512 + scol;
  const unsigned short* srcL = gb.Alo + (size_t)(m0 + srow) * 512 + scol;
  unsigned short* dstH = &AhiS[srow * 72 + scol];
  unsigned short* dstL = &AloS[srow * 72 + scol];
  u16x8 ph = *(const u16x8*)srcH;       // kc=0 prefetch
  u16x8 pl = *(const u16x8*)srcL;

  const int arow = (wr * 16 + l15) * 72;

  for (int kc = 0; kc < 8; kc++){
    __syncthreads();
    *(u16x8*)dstH = ph;
    *(u16x8*)dstL = pl;
    if (kc < 7){
      ph = *(const u16x8*)(srcH + (kc + 1) * 64);   // latency spans compute phase
      pl = *(const u16x8*)(srcL + (kc + 1) * 64);
    }
    __syncthreads();
    #pragma unroll
    for (int s = 0; s < 2; s++){
      int ks = kc * 2 + s;
      bf16x8 ah = *(const bf16x8*)&AhiS[arow + s*32 + quad*8];
      bf16x8 al = *(const bf16x8*)&AloS[arow + s*32 + quad*8];
      #pragma unroll
      for (int t = 0; t < 2; t++){
        int nt = nt0 + wc*2 + t;
        const unsigned short* bp = gb.Bp + (size_t)((nt*16 + ks) * 2) * 512 + lane*8;
        bf16x8 bh = *(const bf16x8*)bp;
        bf16x8 bl = *(const bf16x8*)(bp + 512);
        f32x4& ac = t ? ac1 : ac0;
        ac = __builtin_amdgcn_mfma_f32_16x16x32_bf16(ah, bh, ac, 0, 0, 0);
        ac = __builtin_amdgcn_mfma_f32_16x16x32_bf16(al, bh, ac, 0, 0, 0);
        ac = __builtin_amdgcn_mfma_f32_16x16x32_bf16(ah, bl, ac, 0, 0, 0);
      }
    }
  }

  if (gb.dual){
    // stage [n_local][m_local] bf16 planes in LDS, then coalesced 16B writes
    __syncthreads();
    #pragma unroll
    for (int t = 0; t < 2; t++){
      f32x4 v = t ? ac1 : ac0;
      int nl = wc*32 + t*16 + l15;
      float bs = gb.bias[nt0*16 + nl];
      #pragma unroll
      for (int r = 0; r < 4; r++){
        float val = v[r] + bs;
        int ml = wr*16 + quad*4 + r;
        __bf16 hb = (__bf16)val;
        AhiS[nl*40 + ml] = bfb(hb);
        AloS[nl*40 + ml] = bfb((__bf16)(val - (float)hb));
      }
    }
    __syncthreads();
    int nl = tid >> 2, mq = (tid & 3) * 8;
    int hh2 = (nt0 * 16) >> 6;
    int b2 = m0 >> 9;
    size_t o = (size_t)((b2*8 + hh2)*64 + ((nt0*16 + nl) & 63)) * 512 + (m0 & 511) + mq;
    *(u16x8*)(gb.Chi + o) = *(const u16x8*)&AhiS[nl*40 + mq];
    *(u16x8*)(gb.Clo + o) = *(const u16x8*)&AloS[nl*40 + mq];
    return;
  }

  const int mrow = m0 + wr * 16 + quad * 4;
  #pragma unroll
  for (int t = 0; t < 2; t++){
    f32x4 v = t ? ac1 : ac0;
    int n = nt0*16 + wc*32 + t*16 + l15;
    float bs = gb.bias[n];
    #pragma unroll
    for (int r = 0; r < 4; r++){
      float val = v[r] + bs;
      if (gb.expout) val = __builtin_amdgcn_exp2f(val);
      int m2 = mrow + r;
      if (gb.transposed){
        // eqQ layout: [bh][q][d]
        gb.Cf[(size_t)(((m2 >> 9) * 8 + (n >> 6)) * 512 + (m2 & 511)) * 64 + (n & 63)] = val;
      } else {
        gb.Cf[(size_t)m2 * 512 + n] = val;
      }
    }
  }
}

// ---------------- score + PV: 8 waves, per-wave (i-strip, j-half) quadrants ----------
// grid (4 j-tiles, 8 i-tiles, 16 bh), 512 thr, LDS 51456B -> 2 blocks/CU, 16 waves/CU.
__global__ __launch_bounds__(512, 4) void score_pv(
    const float* __restrict__ eqQ, const float* __restrict__ ekp,
    const float* __restrict__ av2g,
    const unsigned short* __restrict__ vthi, const unsigned short* __restrict__ vtlo,
    float* __restrict__ Og, float* __restrict__ deng){
  __shared__ float SHf[12864];                       // 51456 B
  float* EKt = SHf;                                  // phase1: [64][130] f32 (33280 B)
  float* EQs = SHf + 8320;                           // phase1: [64][64]  f32 (16384 B)
  float* avS = SHf + 12800;                          // persistent [64]
  unsigned short* Ph = (unsigned short*)SHf;         // phase2: [64][136] bf16 (17408 B)
  unsigned short* Pl = (unsigned short*)SHf + 8704;  // phase2: [64][136] bf16 (17408 B)
  float* cmb = SHf + 8704;                           // phase3: [64 i][64 d] f32 (16384 B)

  const int tid = threadIdx.x, lane = tid & 63, w = tid >> 6;   // w 0..7
  const int l15 = lane & 15, quad = lane >> 4;
  const int bh = blockIdx.z, b = bh >> 3, h = bh & 7;
  const int i0 = blockIdx.y * 64;
  const int j0 = blockIdx.x * 128;
  const int wi = w >> 1, jh = w & 1;

  if (tid < 256){ // stage EK transposed [d][j]
    int j = tid >> 1, c0 = (tid & 1) * 32;
    const float* s = ekp + ((size_t)(b * 512) + j0 + j) * 512 + h * 64 + c0;
    #pragma unroll
    for (int u = 0; u < 8; u++){
      f32x4 v = *(const f32x4*)(s + u * 4);
      #pragma unroll
      for (int q = 0; q < 4; q++) EKt[(c0 + u * 4 + q) * 130 + j] = v[q];
    }
  } else {        // stage EQ [i][d] + av
    int t2 = tid - 256;
    int r = t2 >> 2, c = (t2 & 3) * 16;
    const float* s = eqQ + ((size_t)bh * 512 + i0 + r) * 64 + c;
    #pragma unroll
    for (int u = 0; u < 4; u++)
      *(f32x4*)&EQs[r * 64 + c + u * 4] = *(const f32x4*)(s + u * 4);
    if (t2 < 64) avS[t2] = av2g[t2];
  }
  __syncthreads();

  // score: wave (wi,jh) -> rows wi*16..+16, col j = jh*64 + lane
  float acc[16];
  #pragma unroll
  for (int ii = 0; ii < 16; ii++) acc[ii] = 0.f;
  const int jl = jh * 64 + lane;
  for (int d = 0; d < 64; d += 4){
    float ek0 = EKt[(d    ) * 130 + jl];
    float ek1 = EKt[(d + 1) * 130 + jl];
    float ek2 = EKt[(d + 2) * 130 + jl];
    float ek3 = EKt[(d + 3) * 130 + jl];
    f32x4 a4 = *(const f32x4*)&avS[d];
    #pragma unroll
    for (int ii = 0; ii < 16; ii++){
      f32x4 eq4 = *(const f32x4*)&EQs[(wi * 16 + ii) * 64 + d];
      float A = __builtin_fmaf(eq4[0], ek0, 1.f);
      float B = __builtin_fmaf(eq4[1], ek1, 1.f);
      float t = __builtin_fmaf(a4[1], A, a4[0] * B);
      acc[ii] = __builtin_fmaf(t, __builtin_amdgcn_rcpf(A * B), acc[ii]);
      float C = __builtin_fmaf(eq4[2], ek2, 1.f);
      float D = __builtin_fmaf(eq4[3], ek3, 1.f);
      float t2 = __builtin_fmaf(a4[3], C, a4[2] * D);
      acc[ii] = __builtin_fmaf(t2, __builtin_amdgcn_rcpf(C * D), acc[ii]);
    }
  }
  #pragma unroll
  for (int ii = 0; ii < 16; ii++) acc[ii] = __builtin_amdgcn_exp2f(acc[ii]);
  __syncthreads();   // all EKt/EQs reads complete before P/cmb aliasing

  #pragma unroll
  for (int ii = 0; ii < 16; ii++){
    float s2 = acc[ii];
    #pragma unroll
    for (int off = 1; off < 64; off <<= 1) s2 += __shfl_xor(s2, off, 64);
    if (lane == 0) atomicAdd(&deng[bh * 512 + i0 + wi * 16 + ii], s2);
    float e = acc[ii];
    __bf16 hb = (__bf16)e;
    Ph[(wi * 16 + ii) * 136 + jl] = bfb(hb);
    Pl[(wi * 16 + ii) * 136 + jl] = bfb((__bf16)(e - (float)hb));
  }

  // PV over own quadrant (16 i x 64 j x 64 d), K = 64
  f32x4 o0 = {0.f,0.f,0.f,0.f}, o1 = o0, o2 = o0, o3 = o0;
  const size_t vbase = ((size_t)bh * 64) * 512 + j0 + jh * 64;
  #pragma unroll
  for (int ks = 0; ks < 2; ks++){
    int k0 = jh * 64 + ks * 32 + quad * 8;
    bf16x8 pa = *(const bf16x8*)&Ph[(wi * 16 + l15) * 136 + k0];
    bf16x8 pb = *(const bf16x8*)&Pl[(wi * 16 + l15) * 136 + k0];
    #pragma unroll
    for (int nt = 0; nt < 4; nt++){
      size_t vo = vbase + (size_t)(nt * 16 + l15) * 512 + ks * 32 + quad * 8;
      bf16x8 vh = *(const bf16x8*)(vthi + vo);
      bf16x8 vl = *(const bf16x8*)(vtlo + vo);
      f32x4& o = nt == 0 ? o0 : nt == 1 ? o1 : nt == 2 ? o2 : o3;
      o = __builtin_amdgcn_mfma_f32_16x16x32_bf16(pa, vh, o, 0, 0, 0);
      o = __builtin_amdgcn_mfma_f32_16x16x32_bf16(pb, vh, o, 0, 0, 0);
      o = __builtin_amdgcn_mfma_f32_16x16x32_bf16(pa, vl, o, 0, 0, 0);
    }
  }
  // combine j-halves through LDS, then one atomic per element
  if (jh == 1){
    #pragma unroll
    for (int nt = 0; nt < 4; nt++){
      f32x4 o = nt == 0 ? o0 : nt == 1 ? o1 : nt == 2 ? o2 : o3;
      #pragma unroll
      for (int r = 0; r < 4; r++)
        cmb[(wi * 16 + quad * 4 + r) * 64 + nt * 16 + l15] = o[r];
    }
  }
  __syncthreads();
  if (jh == 0){
    #pragma unroll
    for (int nt = 0; nt < 4; nt++){
      f32x4 o = nt == 0 ? o0 : nt == 1 ? o1 : nt == 2 ? o2 : o3;
      int d = nt * 16 + l15;
      #pragma unroll
      for (int r = 0; r < 4; r++){
        int il = wi * 16 + quad * 4 + r;
        float cv = o[r] + cmb[il * 64 + d];
        atomicAdd(&Og[((size_t)bh * 512 + i0 + il) * 64 + d], cv);
      }
    }
  }
}

// ---------------- finish: O/den -> Oh bf16 hi/lo planes ----------------
__global__ __launch_bounds__(256) void finish_oh(
    const float* __restrict__ Og, const float* __restrict__ deng,
    unsigned short* __restrict__ Ohhi, unsigned short* __restrict__ Ohlo){
  int t = blockIdx.x * 256 + threadIdx.x;       // 0..65535
  int bh = t >> 12;
  int i  = (t >> 3) & 511;
  int d0 = (t & 7) * 8;
  float rv = 1.0f / deng[bh * 512 + i];
  const float* src = Og + ((size_t)bh * 512 + i) * 64 + d0;
  f32x4 v0 = *(const f32x4*)src;
  f32x4 v1 = *(const f32x4*)(src + 4);
  u16x8 hh, ll;
  #pragma unroll
  for (int u = 0; u < 8; u++){
    float f = ((u < 4) ? v0[u] : v1[u - 4]) * rv;
    __bf16 hb = (__bf16)f;
    hh[u] = bfb(hb);
    ll[u] = bfb((__bf16)(f - (float)hb));
  }
  size_t o = ((size_t)(bh >> 3) * 512 + i) * 512 + (bh & 7) * 64 + d0;
  *(u16x8*)(Ohhi + o) = hh;
  *(u16x8*)(Ohlo + o) = ll;
}

// ---------------- launch ----------------
extern "C" void kernel_launch(void* const* d_in, const int* in_sizes, int n_in,
                              void* d_out, int out_size, void* d_ws, size_t ws_size,
                              hipStream_t stream){
  const float* q_in = (const float*)d_in[0];
  const float* k_in = (const float*)d_in[1];
  const float* v_in = (const float*)d_in[2];
  const float* Wq_  = (const float*)d_in[3];
  const float* bq_  = (const float*)d_in[4];
  const float* Wk_  = (const float*)d_in[5];
  const float* bk_  = (const float*)d_in[6];
  const float* Wv_  = (const float*)d_in[7];
  const float* bv_  = (const float*)d_in[8];
  const float* Wo_  = (const float*)d_in[9];
  const float* bo_  = (const float*)d_in[10];
  const float* Aq_  = (const float*)d_in[11];
  const float* Ak_  = (const float*)d_in[12];
  const float* av_  = (const float*)d_in[13];

  char* ws = (char*)d_ws;
  unsigned short* W2qp = (unsigned short*)(ws + 0);
  unsigned short* W2kp = (unsigned short*)(ws + 1048576);
  unsigned short* Ohhi = (unsigned short*)(ws + 0);        // reuses W2 region after gemm1
  unsigned short* Ohlo = (unsigned short*)(ws + 1048576);
  unsigned short* Wvp  = (unsigned short*)(ws + 2097152);
  unsigned short* Wop  = (unsigned short*)(ws + 3145728);
  float* b2q  = (float*)(ws + 4194304);
  float* b2k  = (float*)(ws + 4196352);
  float* av2g = (float*)(ws + 4198400);
  float* eqQ  = (float*)(ws + 4198656);
  float* ekp  = (float*)(ws + 6295808);
  unsigned short* vthi = (unsigned short*)(ws + 8392960);
  unsigned short* vtlo = (unsigned short*)(ws + 9441536);
  unsigned short* qhi = (unsigned short*)(ws + 10490112);
  unsigned short* qlo = (unsigned short*)(ws + 11538688);
  unsigned short* khi = (unsigned short*)(ws + 12587264);
  unsigned short* klo = (unsigned short*)(ws + 13635840);
  unsigned short* vhi = (unsigned short*)(ws + 14684416);
  unsigned short* vlo = (unsigned short*)(ws + 15732992);
  float* deng = (float*)(ws + 16781568);     // 32KB
  float* Og   = (float*)(ws + 16814336);     // 2MB, contiguous after deng

  prep_all<<<dim3(1281, 2, 1), 256, 0, stream>>>(Wq_, Aq_, Wk_, Ak_, bq_, bk_, av_,
                                                 Wv_, Wo_, q_in, k_in, v_in,
                                                 W2qp, W2kp, Wvp, Wop,
                                                 qhi, qlo, khi, klo, vhi, vlo,
                                                 b2q, b2k, av2g, deng);

  GemmArgs ga;
  ga.g[0] = { qhi, qlo, W2qp, b2q, eqQ, 0, 0, 1, 1, 0 };
  ga.g[1] = { khi, klo, W2kp, b2k, ekp, 0, 0, 0, 1, 0 };
  ga.g[2] = { vhi, vlo, Wvp,  bv_, 0, vthi, vtlo, 0, 0, 1 };
  gemm_nk<<<dim3(32, 8, 3), 256, 0, stream>>>(ga);

  score_pv<<<dim3(4, 8, 16), 512, 0, stream>>>(eqQ, ekp, av2g, vthi, vtlo, Og, deng);

  finish_oh<<<dim3(256, 1, 1), 256, 0, stream>>>(Og, deng, Ohhi, Ohlo);

  GemmArgs go;
  go.g[0] = { Ohhi, Ohlo, Wop, bo_, (float*)d_out, 0, 0, 0, 0, 0 };
  go.g[1] = go.g[0];
  go.g[2] = go.g[0];
  gemm_nk<<<dim3(32, 8, 1), 256, 0, stream>>>(go);
}